// Round 1
// baseline (24.847 us; speedup 1.0000x reference)
//
#include <hip/hip_runtime.h>
#include <math.h>

// Cox negative log partial likelihood via bucketed suffix sums.
// os_time in [0, 3650) -> histogram of exp(risk) over time buckets,
// inclusive suffix scan gives risk_set_sum[i] = suffix[os_time[i]].
// Single workgroup: all stages fused, one launch.

#define TBLK 1024
#define HSIZE 4096   // next pow2 >= 3650, zero-padded

__global__ __launch_bounds__(TBLK) void cox_nll_kernel(
    const float* __restrict__ risk,
    const int*   __restrict__ os,
    const int*   __restrict__ os_time,
    float*       __restrict__ out,
    int N)
{
    __shared__ float ha[HSIZE];
    __shared__ float hb[HSIZE];
    __shared__ float wsum[TBLK / 64];
    __shared__ float wcnt[TBLK / 64];

    const int tid = threadIdx.x;

    // 1) zero histogram
    for (int t = tid; t < HSIZE; t += TBLK) ha[t] = 0.0f;
    __syncthreads();

    // 2) accumulate exp(risk[j]) into bucket os_time[j] (LDS float atomics;
    //    ~8192/3650 ~= 2.2 adds per bucket, negligible contention)
    for (int i = tid; i < N; i += TBLK) {
        float e = expf(risk[i]);
        atomicAdd(&ha[os_time[i]], e);
    }
    __syncthreads();

    // 3) inclusive suffix scan over HSIZE buckets (Hillis-Steele, ping-pong).
    //    12 iterations of offsets 1..2048; 4 elements per thread per iter.
    float* src = ha;
    float* dst = hb;
    for (int off = 1; off < HSIZE; off <<= 1) {
        for (int t = tid; t < HSIZE; t += TBLK) {
            float v = src[t];
            int u = t + off;
            if (u < HSIZE) v += src[u];
            dst[t] = v;
        }
        __syncthreads();
        float* tmp = src; src = dst; dst = tmp;
    }
    // after an even number (12) of swaps, result lives in `src` (== ha)

    // 4) masked reduction: num = sum over events of (theta - log(suffix)),
    //    den = number of events.
    float num = 0.0f, den = 0.0f;
    for (int i = tid; i < N; i += TBLK) {
        if (os[i]) {
            float theta = risk[i];
            float rss   = src[os_time[i]];
            num += theta - logf(rss);
            den += 1.0f;
        }
    }
    // wave(64) shuffle reduce
    #pragma unroll
    for (int off = 32; off; off >>= 1) {
        num += __shfl_down(num, off, 64);
        den += __shfl_down(den, off, 64);
    }
    const int wid = tid >> 6;
    if ((tid & 63) == 0) { wsum[wid] = num; wcnt[wid] = den; }
    __syncthreads();
    if (tid == 0) {
        float n2 = 0.0f, d2 = 0.0f;
        #pragma unroll
        for (int w = 0; w < TBLK / 64; ++w) { n2 += wsum[w]; d2 += wcnt[w]; }
        out[0] = -n2 / d2;
    }
}

extern "C" void kernel_launch(void* const* d_in, const int* in_sizes, int n_in,
                              void* d_out, int out_size, void* d_ws, size_t ws_size,
                              hipStream_t stream) {
    const float* risk    = (const float*)d_in[0];
    const int*   os      = (const int*)d_in[1];
    const int*   os_time = (const int*)d_in[2];
    float*       out     = (float*)d_out;
    const int N = in_sizes[0];

    cox_nll_kernel<<<1, TBLK, 0, stream>>>(risk, os, os_time, out, N);
}

// Round 2
// 19.911 us; speedup vs baseline: 1.2479x; 1.2479x over previous
//
#include <hip/hip_runtime.h>
#include <math.h>

// Cox negative log partial likelihood via bucketed suffix sums.
// os_time in [0, 3650) -> histogram of exp(risk) over time buckets,
// inclusive suffix scan gives risk_set_sum[i] = suffix[os_time[i]].
// Single workgroup, single launch. Scan is hierarchical (thread-local 4,
// wave shuffle, wave-totals) -> 4 barriers total instead of 12+.

#define TBLK 1024
#define HSIZE 4096   // next pow2 >= 3650, zero-padded
#define NWAVE (TBLK / 64)

__global__ __launch_bounds__(TBLK) void cox_nll_kernel(
    const float* __restrict__ risk,
    const int*   __restrict__ os,
    const int*   __restrict__ os_time,
    float*       __restrict__ out,
    int N)
{
    __shared__ float h[HSIZE];
    __shared__ float wtot[NWAVE];
    __shared__ float wsum[NWAVE];
    __shared__ float wcnt[NWAVE];

    const int tid  = threadIdx.x;
    const int lane = tid & 63;
    const int wid  = tid >> 6;

    // ---- 0) zero histogram (one float4 per thread) ----
    *(float4*)&h[tid * 4] = make_float4(0.f, 0.f, 0.f, 0.f);

    // ---- 1) load all inputs into registers (vectorized, 2 x int4/float4 each) ----
    float4 rv[2]; int4 tv[2]; int4 ev[2];
    #pragma unroll
    for (int k = 0; k < 2; ++k) {
        int i = k * (TBLK * 4) + tid * 4;
        if (i + 3 < N) {
            rv[k] = *(const float4*)&risk[i];
            tv[k] = *(const int4*)&os_time[i];
            ev[k] = *(const int4*)&os[i];
        } else {
            rv[k] = make_float4(0.f, 0.f, 0.f, 0.f);
            tv[k] = make_int4(0, 0, 0, 0);
            ev[k] = make_int4(0, 0, 0, 0);   // ev=0 -> excluded everywhere
        }
    }
    // precompute exp once (used in histogram)
    float ex[2][4];
    #pragma unroll
    for (int k = 0; k < 2; ++k) {
        ex[k][0] = expf(rv[k].x); ex[k][1] = expf(rv[k].y);
        ex[k][2] = expf(rv[k].z); ex[k][3] = expf(rv[k].w);
    }
    __syncthreads();   // h zeroed

    // ---- 2) histogram: LDS float atomics (~2.2 adds/bucket) ----
    // note: padded lanes (i >= N) have ex=exp(0)=1 -- must skip. Use ev-independent
    // validity: recompute the guard.
    #pragma unroll
    for (int k = 0; k < 2; ++k) {
        int i = k * (TBLK * 4) + tid * 4;
        if (i + 3 < N) {
            atomicAdd(&h[tv[k].x], ex[k][0]);
            atomicAdd(&h[tv[k].y], ex[k][1]);
            atomicAdd(&h[tv[k].z], ex[k][2]);
            atomicAdd(&h[tv[k].w], ex[k][3]);
        }
    }
    __syncthreads();   // histogram complete

    // ---- 3) inclusive suffix scan of h[HSIZE] ----
    // thread-local: 4 contiguous buckets
    const int b = tid * 4;
    float4 a = *(float4*)&h[b];
    float s3 = a.w;
    float s2 = a.z + s3;
    float s1 = a.y + s2;
    float s0 = a.x + s1;            // s0 = thread-local total (sum of its 4)

    // wave-level inclusive suffix scan of thread totals (guarded shfl_down)
    float incl = s0;
    #pragma unroll
    for (int off = 1; off < 64; off <<= 1) {
        float o = __shfl_down(incl, off, 64);
        if (lane + off < 64) incl += o;
    }
    // exclusive (higher lanes only) within wave
    float exclLane = __shfl_down(incl, 1, 64);
    if (lane == 63) exclLane = 0.0f;
    // wave total = lane0's inclusive suffix
    if (lane == 0) wtot[wid] = incl;
    __syncthreads();   // wtot ready

    // exclusive sum over higher waves (broadcast LDS reads, wave-uniform loop)
    float exclWave = 0.0f;
    for (int w = wid + 1; w < NWAVE; ++w) exclWave += wtot[w];

    const float add = exclWave + exclLane;
    s0 += add; s1 += add; s2 += add; s3 += add;
    *(float4*)&h[b] = make_float4(s0, s1, s2, s3);
    __syncthreads();   // suffix table ready

    // ---- 4) masked reduction from registers + LDS lookups ----
    float num = 0.0f, den = 0.0f;
    #pragma unroll
    for (int k = 0; k < 2; ++k) {
        if (ev[k].x) { num += rv[k].x - logf(h[tv[k].x]); den += 1.0f; }
        if (ev[k].y) { num += rv[k].y - logf(h[tv[k].y]); den += 1.0f; }
        if (ev[k].z) { num += rv[k].z - logf(h[tv[k].z]); den += 1.0f; }
        if (ev[k].w) { num += rv[k].w - logf(h[tv[k].w]); den += 1.0f; }
    }
    // wave reduce (lane 0 correct under self-return shfl semantics)
    #pragma unroll
    for (int off = 32; off; off >>= 1) {
        num += __shfl_down(num, off, 64);
        den += __shfl_down(den, off, 64);
    }
    if (lane == 0) { wsum[wid] = num; wcnt[wid] = den; }
    __syncthreads();
    if (tid == 0) {
        float n2 = 0.0f, d2 = 0.0f;
        #pragma unroll
        for (int w = 0; w < NWAVE; ++w) { n2 += wsum[w]; d2 += wcnt[w]; }
        out[0] = -n2 / d2;
    }
}

extern "C" void kernel_launch(void* const* d_in, const int* in_sizes, int n_in,
                              void* d_out, int out_size, void* d_ws, size_t ws_size,
                              hipStream_t stream) {
    const float* risk    = (const float*)d_in[0];
    const int*   os      = (const int*)d_in[1];
    const int*   os_time = (const int*)d_in[2];
    float*       out     = (float*)d_out;
    const int N = in_sizes[0];

    cox_nll_kernel<<<1, TBLK, 0, stream>>>(risk, os, os_time, out, N);
}

// Round 3
// 15.234 us; speedup vs baseline: 1.6310x; 1.3071x over previous
//
#include <hip/hip_runtime.h>
#include <math.h>

// Cox negative log partial likelihood, bucketed (os_time in [0,3650)).
// k1: per-block private LDS histograms of exp(theta) and event-counts,
//     plus per-block sum of theta over events -> disjoint d_ws slices.
// k2: one block sums partials, register suffix-scan, and uses
//     sum_events log(rss) == sum_t cnt[t]*log(suffix[t])  (no N-array re-read).

#define HSIZE 4096          // pow2 >= 3650, zero-padded
#define T1 1024
#define T2 1024
#define NW1 (T1 / 64)
#define NW2 (T2 / 64)

__global__ __launch_bounds__(T1) void k_hist(
    const float* __restrict__ risk,
    const int*   __restrict__ os,
    const int*   __restrict__ os_time,
    float*       __restrict__ ws,
    int N, int HB)
{
    __shared__ float he[HSIZE];   // sum of exp(theta) per bucket
    __shared__ float hc[HSIZE];   // event count per bucket (exact small ints in fp32)
    __shared__ float wred[NW1];

    const int tid  = threadIdx.x;
    const int bid  = blockIdx.x;
    const int lane = tid & 63;
    const int wid  = tid >> 6;

    // zero LDS: T1*4 == HSIZE
    *(float4*)&he[tid * 4] = make_float4(0.f, 0.f, 0.f, 0.f);
    *(float4*)&hc[tid * 4] = make_float4(0.f, 0.f, 0.f, 0.f);

    const int i = bid * T1 + tid;
    const bool valid = i < N;
    float th = 0.f; int t = 0, e = 0;
    if (valid) { th = risk[i]; t = os_time[i]; e = os[i]; }
    const float ex = __expf(th);
    __syncthreads();                        // LDS zeroed

    if (valid) {
        atomicAdd(&he[t], ex);
        if (e) atomicAdd(&hc[t], 1.0f);
    }
    // per-block sum of theta over events (shuffle reduce, no extra barrier)
    float num = (valid && e) ? th : 0.f;
    #pragma unroll
    for (int off = 32; off; off >>= 1) num += __shfl_down(num, off, 64);
    if (lane == 0) wred[wid] = num;
    __syncthreads();                        // atomics + wred complete

    // write private hists to disjoint ws slice (overwrites poison fully)
    float* oe = ws + (size_t)bid * (2 * HSIZE);
    *(float4*)&oe[tid * 4]         = *(float4*)&he[tid * 4];
    *(float4*)&oe[HSIZE + tid * 4] = *(float4*)&hc[tid * 4];
    if (tid == 0) {
        float s = 0.f;
        #pragma unroll
        for (int w = 0; w < NW1; ++w) s += wred[w];
        ws[(size_t)HB * (2 * HSIZE) + bid] = s;
    }
}

__global__ __launch_bounds__(T2) void k_final(
    const float* __restrict__ ws,
    float*       __restrict__ out,
    int HB)
{
    __shared__ float wtot[NW2];
    __shared__ float wls[NW2];
    __shared__ float wcs[NW2];

    const int tid  = threadIdx.x;
    const int lane = tid & 63;
    const int wid  = tid >> 6;

    // sum partial hists (coalesced float4, independent loads for MLP)
    float4 e4 = make_float4(0.f, 0.f, 0.f, 0.f);
    float4 c4 = make_float4(0.f, 0.f, 0.f, 0.f);
    for (int b = 0; b < HB; ++b) {
        const float* p = ws + (size_t)b * (2 * HSIZE);
        const float4 a = *(const float4*)&p[tid * 4];
        const float4 c = *(const float4*)&p[HSIZE + tid * 4];
        e4.x += a.x; e4.y += a.y; e4.z += a.z; e4.w += a.w;
        c4.x += c.x; c4.y += c.y; c4.z += c.z; c4.w += c.w;
    }

    // inclusive suffix scan over HSIZE buckets, all in registers/shuffles
    float s3 = e4.w;
    float s2 = e4.z + s3;
    float s1 = e4.y + s2;
    float s0 = e4.x + s1;          // thread-local total of its 4 buckets
    float incl = s0;
    #pragma unroll
    for (int off = 1; off < 64; off <<= 1) {
        float o = __shfl_down(incl, off, 64);
        if (lane + off < 64) incl += o;
    }
    float exclLane = __shfl_down(incl, 1, 64);
    if (lane == 63) exclLane = 0.f;
    if (lane == 0) wtot[wid] = incl;
    __syncthreads();
    float exclWave = 0.f;
    for (int w = wid + 1; w < NW2; ++w) exclWave += wtot[w];
    const float add = exclWave + exclLane;
    s0 += add; s1 += add; s2 += add; s3 += add;

    // per-bucket event contribution: cnt * log(suffix); guard cnt==0 (suffix may be 0)
    float lsum = 0.f;
    lsum += (c4.x > 0.f) ? c4.x * __logf(s0) : 0.f;
    lsum += (c4.y > 0.f) ? c4.y * __logf(s1) : 0.f;
    lsum += (c4.z > 0.f) ? c4.z * __logf(s2) : 0.f;
    lsum += (c4.w > 0.f) ? c4.w * __logf(s3) : 0.f;
    float csum = c4.x + c4.y + c4.z + c4.w;

    #pragma unroll
    for (int off = 32; off; off >>= 1) {
        lsum += __shfl_down(lsum, off, 64);
        csum += __shfl_down(csum, off, 64);
    }
    if (lane == 0) { wls[wid] = lsum; wcs[wid] = csum; }
    __syncthreads();
    if (tid == 0) {
        float L = 0.f, C = 0.f, S = 0.f;
        #pragma unroll
        for (int w = 0; w < NW2; ++w) { L += wls[w]; C += wcs[w]; }
        for (int b = 0; b < HB; ++b) S += ws[(size_t)HB * (2 * HSIZE) + b];
        out[0] = -(S - L) / C;
    }
}

extern "C" void kernel_launch(void* const* d_in, const int* in_sizes, int n_in,
                              void* d_out, int out_size, void* d_ws, size_t ws_size,
                              hipStream_t stream) {
    const float* risk    = (const float*)d_in[0];
    const int*   os      = (const int*)d_in[1];
    const int*   os_time = (const int*)d_in[2];
    float*       out     = (float*)d_out;
    float*       ws      = (float*)d_ws;
    const int N  = in_sizes[0];
    const int HB = (N + T1 - 1) / T1;   // 8 for N=8192

    k_hist<<<HB, T1, 0, stream>>>(risk, os, os_time, ws, N, HB);
    k_final<<<1, T2, 0, stream>>>(ws, out, HB);
}

// Round 5
// 14.836 us; speedup vs baseline: 1.6748x; 1.0268x over previous
//
#include <hip/hip_runtime.h>
#include <math.h>

// Cox negative log partial likelihood, bucketed (os_time in [0,3650)).
// k1: HB=4 blocks, 2 samples/thread; per-block private LDS histograms of
//     exp(theta) and event-counts + per-block sum(theta over events)
//     -> disjoint d_ws slices (fully overwritten, no zeroing race).
// k2: one block, compile-time-unrolled partial-sum (all loads in flight),
//     register suffix-scan, and sum_events log(rss) == sum_t cnt[t]*log(sfx[t]).

#define HSIZE 4096          // pow2 >= 3650, zero-padded
#define T1 1024
#define SPT 2               // samples per thread in k1
#define T2 1024
#define NW1 (T1 / 64)
#define NW2 (T2 / 64)

__global__ __launch_bounds__(T1) void k_hist(
    const float* __restrict__ risk,
    const int*   __restrict__ os,
    const int*   __restrict__ os_time,
    float*       __restrict__ ws,
    int N, int HB)
{
    __shared__ float he[HSIZE];   // sum of exp(theta) per bucket
    __shared__ float hc[HSIZE];   // event count per bucket
    __shared__ float wred[NW1];

    const int tid  = threadIdx.x;
    const int bid  = blockIdx.x;
    const int lane = tid & 63;
    const int wid  = tid >> 6;

    // zero LDS: T1*4 == HSIZE
    *(float4*)&he[tid * 4] = make_float4(0.f, 0.f, 0.f, 0.f);
    *(float4*)&hc[tid * 4] = make_float4(0.f, 0.f, 0.f, 0.f);

    // vectorized 2-sample load
    const int i0 = (bid * T1 + tid) * SPT;
    float th[SPT]; int tt[SPT]; int ee[SPT]; bool va[SPT];
    if (i0 + SPT - 1 < N) {
        float2 r2 = *(const float2*)&risk[i0];
        int2   t2 = *(const int2*)&os_time[i0];
        int2   e2 = *(const int2*)&os[i0];
        th[0] = r2.x; th[1] = r2.y;
        tt[0] = t2.x; tt[1] = t2.y;
        ee[0] = e2.x; ee[1] = e2.y;
        va[0] = va[1] = true;
    } else {
        #pragma unroll
        for (int k = 0; k < SPT; ++k) {
            int i = i0 + k;
            va[k] = i < N;
            th[k] = va[k] ? risk[i] : 0.f;
            tt[k] = va[k] ? os_time[i] : 0;
            ee[k] = va[k] ? os[i] : 0;
        }
    }
    float ex[SPT];
    #pragma unroll
    for (int k = 0; k < SPT; ++k) ex[k] = __expf(th[k]);
    __syncthreads();                        // LDS zeroed

    #pragma unroll
    for (int k = 0; k < SPT; ++k) {
        if (va[k]) {
            atomicAdd(&he[tt[k]], ex[k]);
            if (ee[k]) atomicAdd(&hc[tt[k]], 1.0f);
        }
    }
    // per-block sum of theta over events
    float num = 0.f;
    #pragma unroll
    for (int k = 0; k < SPT; ++k) if (va[k] && ee[k]) num += th[k];
    #pragma unroll
    for (int off = 32; off; off >>= 1) num += __shfl_down(num, off, 64);
    if (lane == 0) wred[wid] = num;
    __syncthreads();                        // atomics + wred complete

    float* oe = ws + (size_t)bid * (2 * HSIZE);
    *(float4*)&oe[tid * 4]         = *(float4*)&he[tid * 4];
    *(float4*)&oe[HSIZE + tid * 4] = *(float4*)&hc[tid * 4];
    if (tid == 0) {
        float s = 0.f;
        #pragma unroll
        for (int w = 0; w < NW1; ++w) s += wred[w];
        ws[(size_t)HB * (2 * HSIZE) + bid] = s;
    }
}

template <int HBC>
__device__ __forceinline__ void k_final_body(
    const float* __restrict__ ws, float* __restrict__ out, int HB)
{
    __shared__ float wtot[NW2];
    __shared__ float wls[NW2];
    __shared__ float wcs[NW2];

    const int tid  = threadIdx.x;
    const int lane = tid & 63;
    const int wid  = tid >> 6;

    float4 e4 = make_float4(0.f, 0.f, 0.f, 0.f);
    float4 c4 = make_float4(0.f, 0.f, 0.f, 0.f);
    if constexpr (HBC > 0) {
        // compile-time bound: all loads issue before accumulation
        float4 ea[HBC], ca[HBC];
        #pragma unroll
        for (int b = 0; b < HBC; ++b) {
            const float* p = ws + (size_t)b * (2 * HSIZE);
            ea[b] = *(const float4*)&p[tid * 4];
            ca[b] = *(const float4*)&p[HSIZE + tid * 4];
        }
        #pragma unroll
        for (int b = 0; b < HBC; ++b) {
            e4.x += ea[b].x; e4.y += ea[b].y; e4.z += ea[b].z; e4.w += ea[b].w;
            c4.x += ca[b].x; c4.y += ca[b].y; c4.z += ca[b].z; c4.w += ca[b].w;
        }
    } else {
        for (int b = 0; b < HB; ++b) {
            const float* p = ws + (size_t)b * (2 * HSIZE);
            const float4 a = *(const float4*)&p[tid * 4];
            const float4 c = *(const float4*)&p[HSIZE + tid * 4];
            e4.x += a.x; e4.y += a.y; e4.z += a.z; e4.w += a.w;
            c4.x += c.x; c4.y += c.y; c4.z += c.z; c4.w += c.w;
        }
    }
    const int HBr = (HBC > 0) ? HBC : HB;

    // inclusive suffix scan, registers + shuffles
    float s3 = e4.w;
    float s2 = e4.z + s3;
    float s1 = e4.y + s2;
    float s0 = e4.x + s1;
    float incl = s0;
    #pragma unroll
    for (int off = 1; off < 64; off <<= 1) {
        float o = __shfl_down(incl, off, 64);
        if (lane + off < 64) incl += o;
    }
    float exclLane = __shfl_down(incl, 1, 64);
    if (lane == 63) exclLane = 0.f;
    if (lane == 0) wtot[wid] = incl;
    __syncthreads();
    float exclWave = 0.f;
    for (int w = wid + 1; w < NW2; ++w) exclWave += wtot[w];
    const float add = exclWave + exclLane;
    s0 += add; s1 += add; s2 += add; s3 += add;

    float lsum = 0.f;
    lsum += (c4.x > 0.f) ? c4.x * __logf(s0) : 0.f;
    lsum += (c4.y > 0.f) ? c4.y * __logf(s1) : 0.f;
    lsum += (c4.z > 0.f) ? c4.z * __logf(s2) : 0.f;
    lsum += (c4.w > 0.f) ? c4.w * __logf(s3) : 0.f;
    float csum = c4.x + c4.y + c4.z + c4.w;

    #pragma unroll
    for (int off = 32; off; off >>= 1) {
        lsum += __shfl_down(lsum, off, 64);
        csum += __shfl_down(csum, off, 64);
    }
    if (lane == 0) { wls[wid] = lsum; wcs[wid] = csum; }
    __syncthreads();
    if (tid == 0) {
        float L = 0.f, C = 0.f, S = 0.f;
        #pragma unroll
        for (int w = 0; w < NW2; ++w) { L += wls[w]; C += wcs[w]; }
        for (int b = 0; b < HBr; ++b) S += ws[(size_t)HBr * (2 * HSIZE) + b];
        out[0] = -(S - L) / C;
    }
}

template <int HBC>
__global__ __launch_bounds__(T2) void k_final(
    const float* __restrict__ ws, float* __restrict__ out)
{
    k_final_body<HBC>(ws, out, HBC);
}

__global__ __launch_bounds__(T2) void k_final_gen(
    const float* __restrict__ ws, float* __restrict__ out, int HB)
{
    k_final_body<0>(ws, out, HB);
}

extern "C" void kernel_launch(void* const* d_in, const int* in_sizes, int n_in,
                              void* d_out, int out_size, void* d_ws, size_t ws_size,
                              hipStream_t stream) {
    const float* risk    = (const float*)d_in[0];
    const int*   os      = (const int*)d_in[1];
    const int*   os_time = (const int*)d_in[2];
    float*       out     = (float*)d_out;
    float*       ws      = (float*)d_ws;
    const int N  = in_sizes[0];
    const int HB = (N + T1 * SPT - 1) / (T1 * SPT);   // 4 for N=8192

    k_hist<<<HB, T1, 0, stream>>>(risk, os, os_time, ws, N, HB);
    if (HB == 4)      k_final<4><<<1, T2, 0, stream>>>(ws, out);
    else if (HB == 8) k_final<8><<<1, T2, 0, stream>>>(ws, out);
    else              k_final_gen<<<1, T2, 0, stream>>>(ws, out, HB);
}